// Round 8
// baseline (1000.200 us; speedup 1.0000x reference)
//
#include <hip/hip_runtime.h>
#include <stdint.h>

typedef unsigned short u16;
using frag8 = __attribute__((ext_vector_type(8))) short;
using f32x4 = __attribute__((ext_vector_type(4))) float;

#define NTOK 32768
#define FDIM 512

__device__ __forceinline__ float bflo(uint32_t p){ union{uint32_t u; float f;} v; v.u = p<<16; return v.f; }
__device__ __forceinline__ float bfhi(uint32_t p){ union{uint32_t u; float f;} v; v.u = p & 0xffff0000u; return v.f; }
__device__ __forceinline__ float bf1(u16 x){ union{uint32_t u; float f;} v; v.u = ((uint32_t)x)<<16; return v.f; }
__device__ __forceinline__ u16 f2bf(float f){
  union{float f; uint32_t u;} v; v.f = f;
  uint32_t u = v.u;
  u += 0x7fffu + ((u>>16)&1u);   // round-to-nearest-even
  return (u16)(u>>16);
}

__device__ __forceinline__ void async16(const void* g, void* l){
  __builtin_amdgcn_global_load_lds((const __attribute__((address_space(1))) uint32_t*)g,
                                   (__attribute__((address_space(3))) uint32_t*)l, 16, 0, 0);
}

// -------------------- embedding + positional encoding (bf16 x only) --------------------
__global__ __launch_bounds__(256) void embed_kernel(const int* __restrict__ text,
    const float* __restrict__ emb, const float* __restrict__ pe,
    u16* __restrict__ xb, const int tok0){
  const int gid = blockIdx.x*256 + threadIdx.x;
  const int base = gid*4;
  const int tl = base >> 9;
  const int f  = base & 511;
  const int tg = tl + tok0;
  const int s  = tg & 511;
  const int tok = text[tg];
  const float4 e4 = *(const float4*)(emb + (size_t)tok*FDIM + f);
  const float4 p4 = *(const float4*)(pe  + (size_t)s*FDIM + f);
  ushort4 ob;
  ob.x = f2bf(e4.x + p4.x);
  ob.y = f2bf(e4.y + p4.y);
  ob.z = f2bf(e4.z + p4.z);
  ob.w = f2bf(e4.w + p4.w);
  *(ushort4*)(xb + base) = ob;
}

// -------------------- weight transpose + fp32->bf16: WT[lay][n][k], n: Wq|Wk|Wv|Wf --------------------
__global__ __launch_bounds__(256) void transpose_w(const float* __restrict__ Wq,
    const float* __restrict__ Wk, const float* __restrict__ Wv, const float* __restrict__ Wf,
    u16* __restrict__ WT){
  const int gid = blockIdx.x*256 + threadIdx.x;
  const int n   = gid & 2047;
  const int k8  = (gid>>11) & 63;
  const int lay = gid >> 17;
  const float* src; int col;
  if      (n <  512){ src = Wq; col = n;      }
  else if (n < 1024){ src = Wk; col = n-512;  }
  else if (n < 1536){ src = Wv; col = n-1024; }
  else              { src = Wf; col = n-1536; }
  src += (size_t)lay*FDIM*FDIM;
  u16 vals[8] __attribute__((aligned(16)));
  #pragma unroll
  for (int i=0;i<8;i++) vals[i] = f2bf(src[(size_t)(k8*8+i)*FDIM + col]);
  *(int4*)(WT + ((size_t)lay*2048 + n)*FDIM + k8*8) = *(const int4*)vals;
}

// -------------------- 256x256 8-phase pipelined MFMA GEMM (R6 structure, best measured: 66us) ----
// QKV only: C = xb * WT^T + bias(q|k|v by column range), ldC=1536.
__global__ __launch_bounds__(512, 2) void gemm8p(
    const u16* __restrict__ A, const u16* __restrict__ BT,
    const float* __restrict__ b0, const float* __restrict__ b1, const float* __restrict__ b2,
    u16* __restrict__ C, const int ldC, const int NB){
  __shared__ __attribute__((aligned(16))) char lds[131072];
  const int nwg = gridDim.x;
  const int orig = blockIdx.x;
  const int wg = ((nwg & 7)==0) ? ((orig&7)*(nwg>>3) + (orig>>3)) : orig;
  const int nblk = wg % NB, mblk = wg / NB;
  const int m0 = mblk<<8, n0 = nblk<<8;
  const int tid = threadIdx.x;
  const int wid = tid>>6, l = tid&63;
  const int lm = l&15, quad = l>>4;
  const int wm = wid>>2, wn = wid&3;

  const int cg = (l&3) ^ ((l>>3)&3);
  const char* aSrc = (const char*)A  + ((size_t)(m0 + (wid>>2)*128 + (wid&3)*16 + (l>>2)))*1024 + cg*16;
  const char* bSrc = (const char*)BT + ((size_t)(n0 + (wid>>1)*64  + (wid&1)*16 + (l>>2)))*1024 + cg*16;
  char* ldsAs = lds + wid*1024;
  char* ldsBs = lds + 65536 + wid*1024;

#define STGA(kt, kw, mh) async16(aSrc + (mh)*65536 + (kt)*128 + (kw)*64, \
                                 ldsAs + (((kt)&1)*32768) + (kw)*16384 + (mh)*8192)
#define STGB(kt, kw, nh) async16(bSrc + (nh)*32768 + (kt)*128 + (kw)*64, \
                                 ldsBs + (((kt)&1)*32768) + (kw)*16384 + (nh)*8192)

  f32x4 acc[8][4];
  #pragma unroll
  for (int i=0;i<8;i++)
    #pragma unroll
    for (int j=0;j<4;j++){ f32x4 z = {0.f,0.f,0.f,0.f}; acc[i][j] = z; }

  const int csw = (quad ^ ((l>>1)&3))*16;
  const char* aRd = lds + wm*4096 + lm*64 + csw;
  const char* bRd = lds + 65536 + wn*2048 + lm*64 + csw;

  frag8 a[4][2], bR[2][2][2];

  STGA(0,0,0); STGA(0,1,0); STGB(0,0,0); STGB(0,1,0); STGB(0,0,1); STGB(0,1,1); STGA(0,0,1); STGA(0,1,1);
  STGA(1,0,0); STGA(1,1,0); STGB(1,0,0); STGB(1,1,0); STGB(1,0,1); STGB(1,1,1);
  asm volatile("s_waitcnt vmcnt(6)" ::: "memory");
  __builtin_amdgcn_s_barrier();

#define RDA(BUF, MH) { _Pragma("unroll") for (int mi_=0;mi_<4;mi_++){ \
    a[mi_][0] = *(const frag8*)(aRd + (BUF)*32768 + (MH)*8192 + mi_*1024); \
    a[mi_][1] = *(const frag8*)(aRd + (BUF)*32768 + 16384 + (MH)*8192 + mi_*1024); } }
#define RDB(BUF, NH) { _Pragma("unroll") for (int nj_=0;nj_<2;nj_++){ \
    bR[NH][nj_][0] = *(const frag8*)(bRd + (BUF)*32768 + (NH)*8192 + nj_*1024); \
    bR[NH][nj_][1] = *(const frag8*)(bRd + (BUF)*32768 + 16384 + (NH)*8192 + nj_*1024); } }
#define MM(MH, NH) { __builtin_amdgcn_s_setprio(1); \
  _Pragma("unroll") for (int kw_=0;kw_<2;kw_++) \
  _Pragma("unroll") for (int mi_=0;mi_<4;mi_++) \
  _Pragma("unroll") for (int nj_=0;nj_<2;nj_++) \
    acc[(MH)*4+mi_][(NH)*2+nj_] = __builtin_amdgcn_mfma_f32_16x16x32_bf16( \
        a[mi_][kw_], bR[NH][nj_][kw_], acc[(MH)*4+mi_][(NH)*2+nj_], 0,0,0); \
  __builtin_amdgcn_s_setprio(0); }
#define BAR __builtin_amdgcn_s_barrier()

#define ITER(T, FULL) { \
  /* P0 */ RDA(((T)&1),0); RDB(((T)&1),0); STGA((T)+1,0,1); STGA((T)+1,1,1); \
           BAR; MM(0,0); BAR; \
  /* P1 */ RDB(((T)&1),1); if (FULL){ STGA((T)+2,0,0); STGA((T)+2,1,0); } \
           BAR; MM(0,1); BAR; \
  /* P2 */ RDA(((T)&1),1); if (FULL){ STGB((T)+2,0,0); STGB((T)+2,1,0); } \
           BAR; MM(1,0); BAR; \
  /* P3 */ if (FULL){ STGB((T)+2,0,1); STGB((T)+2,1,1); } \
           BAR; MM(1,1); \
           if (FULL){ asm volatile("s_waitcnt vmcnt(6)" ::: "memory"); } \
           else     { asm volatile("s_waitcnt vmcnt(0)" ::: "memory"); } \
           BAR; \
  /* P4 */ RDA((((T)+1)&1),0); RDB((((T)+1)&1),0); if (FULL){ STGA((T)+2,0,1); STGA((T)+2,1,1); } \
           BAR; MM(0,0); BAR; \
  /* P5 */ RDB((((T)+1)&1),1); if (FULL){ STGA((T)+3,0,0); STGA((T)+3,1,0); } \
           BAR; MM(0,1); BAR; \
  /* P6 */ RDA((((T)+1)&1),1); if (FULL){ STGB((T)+3,0,0); STGB((T)+3,1,0); } \
           BAR; MM(1,0); BAR; \
  /* P7 */ if (FULL){ STGB((T)+3,0,1); STGB((T)+3,1,1); } \
           BAR; MM(1,1); \
           if (FULL){ asm volatile("s_waitcnt vmcnt(6)" ::: "memory"); } \
           BAR; \
}

  ITER(0,1)
  ITER(2,1)
  ITER(4,1)
  ITER(6,0)

#undef ITER
#undef BAR
#undef MM
#undef RDB
#undef RDA
#undef STGB
#undef STGA

  float bias[4]; int cols[4];
  #pragma unroll
  for (int nj=0;nj<4;nj++){
    const int c = n0 + wn*64 + nj*16 + lm;
    cols[nj] = c;
    bias[nj] = (c<512 ? b0[c] : (c<1024 ? b1[c-512] : b2[c-1024]));
  }
  #pragma unroll
  for (int mi=0; mi<8; mi++){
    const int rbase = m0 + wm*128 + mi*16 + quad*4;
    #pragma unroll
    for (int r=0;r<4;r++){
      const size_t row = (size_t)(rbase + r);
      #pragma unroll
      for (int nj=0;nj<4;nj++){
        float v = acc[mi][nj][r] + bias[nj];
        C[row*(size_t)ldC + cols[nj]] = f2bf(v);
      }
    }
  }
}

// -------------------- per-token head-attention + residual(bf16) + LN1 (1 wave = 1 token) --------------------
__global__ __launch_bounds__(256) void attn_ln1(const u16* __restrict__ qkvb,
    const u16* __restrict__ xb, const float* __restrict__ gam, const float* __restrict__ bet,
    u16* __restrict__ y1b){
  __shared__ __attribute__((aligned(16))) u16 sQ[4][1536];
  __shared__ float sWt[4][64];
  const int tid = threadIdx.x, w = tid>>6, l = tid&63;
  const int t = blockIdx.x*4 + w;
  {
    const int4* src = (const int4*)(qkvb + (size_t)t*1536);
    int4* dst = (int4*)(&sQ[w][0]);
    #pragma unroll
    for (int i=0;i<3;i++) dst[i*64 + l] = src[i*64 + l];
  }
  __syncthreads();
  const int h = l>>3, g = l&7;
  const u16* qrow = &sQ[w][h*64];
  const u16* krow = &sQ[w][512 + g*64];
  float sc = 0.f;
  const int dstart = (l&31)*2;
  #pragma unroll
  for (int i=0;i<32;i++){
    const int d = (dstart + 2*i) & 63;
    const uint32_t qp = *(const uint32_t*)(qrow + d);
    const uint32_t kp = *(const uint32_t*)(krow + d);
    sc += bflo(qp)*bflo(kp) + bfhi(qp)*bfhi(kp);
  }
  float mx = sc;
  mx = fmaxf(mx, __shfl_xor(mx,1));
  mx = fmaxf(mx, __shfl_xor(mx,2));
  mx = fmaxf(mx, __shfl_xor(mx,4));
  const float e = __expf(sc - mx);
  float ssum = e;
  ssum += __shfl_xor(ssum,1);
  ssum += __shfl_xor(ssum,2);
  ssum += __shfl_xor(ssum,4);
  sWt[w][l] = e / ssum;
  __syncthreads();
  float wt[8];
  #pragma unroll
  for (int gg=0;gg<8;gg++) wt[gg] = sWt[w][h*8+gg];
  float att[8] = {0,0,0,0,0,0,0,0};
  const int d0 = (l&7)*8;
  #pragma unroll
  for (int gg=0;gg<8;gg++){
    const int4 vv = *(const int4*)(&sQ[w][1024 + gg*64 + d0]);
    const uint32_t* vp = (const uint32_t*)&vv;
    #pragma unroll
    for (int p=0;p<4;p++){
      att[2*p]   += wt[gg]*bflo(vp[p]);
      att[2*p+1] += wt[gg]*bfhi(vp[p]);
    }
  }
  const size_t rb = (size_t)t*FDIM + l*8;
  const int4 xv = *(const int4*)(xb + rb);
  const uint32_t* xp = (const uint32_t*)&xv;
  float y[8]; float s1=0.f, s2=0.f;
  #pragma unroll
  for (int p=0;p<4;p++){
    y[2*p]   = att[2*p]   + bflo(xp[p]);
    y[2*p+1] = att[2*p+1] + bfhi(xp[p]);
  }
  #pragma unroll
  for (int j=0;j<8;j++){ s1 += y[j]; s2 += y[j]*y[j]; }
  #pragma unroll
  for (int off=1; off<64; off<<=1){ s1 += __shfl_xor(s1,off); s2 += __shfl_xor(s2,off); }
  const float mean = s1*(1.f/512.f);
  const float var  = s2*(1.f/512.f) - mean*mean;
  const float rstd = rsqrtf(var + 1e-5f);
  const float4 g0 = *(const float4*)(gam + l*8);
  const float4 g1v = *(const float4*)(gam + l*8 + 4);
  const float4 b0v = *(const float4*)(bet + l*8);
  const float4 b1v = *(const float4*)(bet + l*8 + 4);
  float of[8];
  of[0]=(y[0]-mean)*rstd*g0.x + b0v.x;
  of[1]=(y[1]-mean)*rstd*g0.y + b0v.y;
  of[2]=(y[2]-mean)*rstd*g0.z + b0v.z;
  of[3]=(y[3]-mean)*rstd*g0.w + b0v.w;
  of[4]=(y[4]-mean)*rstd*g1v.x + b1v.x;
  of[5]=(y[5]-mean)*rstd*g1v.y + b1v.y;
  of[6]=(y[6]-mean)*rstd*g1v.z + b1v.z;
  of[7]=(y[7]-mean)*rstd*g1v.w + b1v.w;
  u16 ob[8] __attribute__((aligned(16)));
  #pragma unroll
  for (int j=0;j<8;j++) ob[j] = f2bf(of[j]);
  *(int4*)(y1b + rb) = *(const int4*)ob;
}

// -------------------- FF GEMM (64x512 tile, full rows) + bias + residual + LN2 fused --------------------
// 2 blocks/CU is the design invariant (R5 failed at 1 blk/CU): LDS = A-pairs 16K + B 64K = 80K exactly.
// K-loop: 16 tiles BK=32. B ring-2 (slot t&1), staged 4 calls/tile; A ring-2 of PAIRS (64 rows x 64 k
// = 8KB, slot (t>>1)&1), staged 1 call per pair. All stages issue AFTER the end-of-tile barrier ->
// the target slot's reads are complete (ring-2 race-free). Counted vmcnt at tile top (before barrier):
// even t -> 4 (newer = B_{t+1}), odd t -> 5 (newer = B4+Apair1); t=14 -> 4, t=15 -> 0.
// B swizzle = R1's measured-zero-conflict pattern; A swizzle c^(row&7) (2 lanes/16B slot = free).
// Epilogue: bias + y1-residual on f32 acc, LN2 row stats via partials in dead A region (R5-verified).
__global__ __launch_bounds__(512, 4) void ff_ln2(
    const u16* __restrict__ y1, const u16* __restrict__ WTf,
    const float* __restrict__ bfv,
    const float* __restrict__ g2, const float* __restrict__ be2,
    u16* __restrict__ xb, float* __restrict__ outp, const int final_){
  __shared__ __attribute__((aligned(16))) char lds[81920];   // A 16K | B 64K
  const int m0 = blockIdx.x << 6;
  const int tid = threadIdx.x;
  const int wid = tid>>6, l = tid&63;
  const int lm = l&15, quad = l>>4;

  // A stage: thread t -> LDS (row=t>>3, chunk=t&7) linear; global chunk = (t&7)^((t>>3)&7).
  const char* aSrc = (const char*)y1 + ((size_t)(m0 + (tid>>3)))*1024 + ((tid&7) ^ ((tid>>3)&7))*16;
  // B stage: R1 pattern (rows wid*16+(l>>2) per 8KB call, chunk (l&3)^((l>>3)&3)).
  const char* bSrc = (const char*)WTf + ((size_t)(wid*16 + (l>>2)))*1024 + ((l&3) ^ ((l>>3)&3))*16;
  char* ldsA = lds + wid*1024;
  char* ldsB = lds + 16384 + wid*1024;

#define STA(P) async16(aSrc + (P)*128, ldsA + ((P)&1)*8192)
#define STB(T) { _Pragma("unroll") for (int r_=0;r_<4;r_++) \
    async16(bSrc + (size_t)r_*131072 + (T)*64, ldsB + ((T)&1)*32768 + r_*8192); }

  f32x4 acc[4][4];
  #pragma unroll
  for (int i=0;i<4;i++)
    #pragma unroll
    for (int j=0;j<4;j++){ f32x4 z = {0.f,0.f,0.f,0.f}; acc[i][j] = z; }

  // prologue: Apair0 (1) + B0 (4) + B1 (4)
  STA(0); STB(0) STB(1)

#define FTL(T_, VMC, DOB, DOA) { \
    asm volatile("s_waitcnt vmcnt(" #VMC ")" ::: "memory"); \
    __builtin_amdgcn_s_barrier(); \
    asm volatile("" ::: "memory"); \
    const char* sA_ = lds + (((T_)>>1)&1)*8192; \
    const char* sB_ = lds + 16384 + ((T_)&1)*32768; \
    frag8 af_[4], bf_[4]; \
    _Pragma("unroll") \
    for (int mi_=0;mi_<4;mi_++) \
      af_[mi_] = *(const frag8*)(sA_ + (mi_*16+lm)*128 + ((((T_)&1)*4+quad)^(lm&7))*16); \
    _Pragma("unroll") \
    for (int nj_=0;nj_<4;nj_++) \
      bf_[nj_] = *(const frag8*)(sB_ + (wid*64 + nj_*16 + lm)*64 + (quad^((lm>>1)&3))*16); \
    __builtin_amdgcn_s_setprio(1); \
    _Pragma("unroll") \
    for (int mi_=0;mi_<4;mi_++) \
      _Pragma("unroll") \
      for (int nj_=0;nj_<4;nj_++) \
        acc[mi_][nj_] = __builtin_amdgcn_mfma_f32_16x16x32_bf16(af_[mi_], bf_[nj_], acc[mi_][nj_], 0,0,0); \
    __builtin_amdgcn_s_setprio(0); \
    __builtin_amdgcn_s_barrier(); \
    if (DOB){ STB((T_)+2) } \
    if (DOA){ STA(((T_)>>1)+1); } \
  }

  FTL(0,4,1,1)   FTL(1,5,1,0)
  FTL(2,4,1,1)   FTL(3,5,1,0)
  FTL(4,4,1,1)   FTL(5,5,1,0)
  FTL(6,4,1,1)   FTL(7,5,1,0)
  FTL(8,4,1,1)   FTL(9,5,1,0)
  FTL(10,4,1,1)  FTL(11,5,1,0)
  FTL(12,4,1,1)  FTL(13,5,1,0)
  FTL(14,4,0,0)  FTL(15,0,0,0)
#undef FTL
#undef STB
#undef STA

  // ---- epilogue: bias + residual(y1) + LN2 on f32 z + write ----
  float* ln2S = (float*)lds;          // dead A region (4KB used); all A reads done at last barrier
  int cols[4]; float bia[4], gg2[4], bb2[4];
  #pragma unroll
  for (int nj=0;nj<4;nj++){
    const int c = wid*64 + nj*16 + lm;
    cols[nj] = c; bia[nj] = bfv[c]; gg2[nj] = g2[c]; bb2[nj] = be2[c];
  }
  #pragma unroll
  for (int mi=0;mi<4;mi++){
    #pragma unroll
    for (int r=0;r<4;r++){
      const int row_l = mi*16 + quad*4 + r;
      const size_t rg = (size_t)(m0 + row_l)*FDIM;
      float s1 = 0.f, s2 = 0.f;
      #pragma unroll
      for (int nj=0;nj<4;nj++){
        const float v = acc[mi][nj][r] + bia[nj] + bf1(y1[rg + cols[nj]]);
        acc[mi][nj][r] = v;
        s1 += v; s2 += v*v;
      }
      s1 += __shfl_xor(s1,1); s2 += __shfl_xor(s2,1);
      s1 += __shfl_xor(s1,2); s2 += __shfl_xor(s2,2);
      s1 += __shfl_xor(s1,4); s2 += __shfl_xor(s2,4);
      s1 += __shfl_xor(s1,8); s2 += __shfl_xor(s2,8);
      if (lm == 0){
        ln2S[(row_l*8 + wid)*2]     = s1;
        ln2S[(row_l*8 + wid)*2 + 1] = s2;
      }
    }
  }
  __syncthreads();
  #pragma unroll
  for (int mi=0;mi<4;mi++){
    #pragma unroll
    for (int r=0;r<4;r++){
      const int row_l = mi*16 + quad*4 + r;
      float s1t = 0.f, s2t = 0.f;
      #pragma unroll
      for (int w=0;w<8;w++){
        s1t += ln2S[(row_l*8 + w)*2];
        s2t += ln2S[(row_l*8 + w)*2 + 1];
      }
      const float mean = s1t*(1.f/512.f);
      const float var  = s2t*(1.f/512.f) - mean*mean;
      const float rstd = rsqrtf(var + 1e-5f);
      const size_t rg = (size_t)(m0 + row_l)*FDIM;
      if (final_){
        #pragma unroll
        for (int nj=0;nj<4;nj++)
          outp[rg + cols[nj]] = (acc[mi][nj][r]-mean)*rstd*gg2[nj] + bb2[nj];
      } else {
        #pragma unroll
        for (int nj=0;nj<4;nj++)
          xb[rg + cols[nj]] = f2bf((acc[mi][nj][r]-mean)*rstd*gg2[nj] + bb2[nj]);
      }
    }
  }
}

extern "C" void kernel_launch(void* const* d_in, const int* in_sizes, int n_in,
                              void* d_out, int out_size, void* d_ws, size_t ws_size,
                              hipStream_t stream){
  const int*   text = (const int*)d_in[0];
  const float* emb = (const float*)d_in[1];
  const float* pe  = (const float*)d_in[2];
  const float* Wq  = (const float*)d_in[3];
  const float* bq  = (const float*)d_in[4];
  const float* Wk  = (const float*)d_in[5];
  const float* bk  = (const float*)d_in[6];
  const float* Wv  = (const float*)d_in[7];
  const float* bv  = (const float*)d_in[8];
  const float* g1  = (const float*)d_in[9];
  const float* be1 = (const float*)d_in[10];
  const float* Wf  = (const float*)d_in[11];
  const float* bf_ = (const float*)d_in[12];
  const float* g2  = (const float*)d_in[13];
  const float* be2 = (const float*)d_in[14];
  float* outp = (float*)d_out;               // reference output dtype = float32

  // ---- layout: WT 12.6 MB + per-token {xb 1024 + y1b 1024 + qkv 3072} = 5120 B
  const size_t wtB = (size_t)6*2048*512*2;
  int T = NTOK;
  while (T > 2048 && wtB + (size_t)T*5120 > ws_size) T >>= 1;

  char* ws = (char*)d_ws;
  u16*   WT  = (u16*)ws;
  char*  act = ws + wtB;
  u16*   xb  = (u16*)act;                       // T*1024 B (updated in place per layer)
  u16*   y1b = (u16*)(act + (size_t)T*1024);    // T*1024 B
  u16*   qkv = (u16*)(act + (size_t)T*2048);    // T*3072 B

  hipLaunchKernelGGL(transpose_w, dim3(3072), dim3(256), 0, stream, Wq, Wk, Wv, Wf, WT);

  const int chunks = NTOK / T;
  for (int c = 0; c < chunks; c++){
    const int tok0 = c*T;
    hipLaunchKernelGGL(embed_kernel, dim3(T/2), dim3(256), 0, stream, text, emb, pe, xb, tok0);
    for (int lay=0; lay<6; lay++){
      const u16* WTl = WT + (size_t)lay*2048*FDIM;
      hipLaunchKernelGGL(gemm8p, dim3((T/256)*6), dim3(512), 0, stream,
          xb, WTl, bq + lay*FDIM, bk + lay*FDIM, bv + lay*FDIM, qkv, 1536, 6);
      hipLaunchKernelGGL(attn_ln1, dim3(T/4), dim3(256), 0, stream,
          qkv, xb, g1 + lay*FDIM, be1 + lay*FDIM, y1b);
      hipLaunchKernelGGL(ff_ln2, dim3(T/64), dim3(512), 0, stream,
          y1b, WTl + (size_t)1536*FDIM, bf_ + lay*FDIM,
          g2 + lay*FDIM, be2 + lay*FDIM,
          xb, outp + (size_t)tok0*FDIM, (lay==5)?1:0);
    }
  }
}